// Round 1
// baseline (942.966 us; speedup 1.0000x reference)
//
#include <hip/hip_runtime.h>
#include <hip/hip_bf16.h>

#define TDIM 1024
#define NEXP 8
#define NHID 4096

typedef __hip_bfloat16 bf16;
typedef __attribute__((ext_vector_type(8))) short bf16x8;
typedef __attribute__((ext_vector_type(4))) float f32x4;

__device__ __forceinline__ void gload_lds16(void* lds, const void* g) {
  __builtin_amdgcn_global_load_lds(
      (const __attribute__((address_space(1))) unsigned int*)g,
      (__attribute__((address_space(3))) unsigned int*)lds, 16, 0, 0);
}

__device__ __forceinline__ unsigned short f2bf_bits(float f) {
  __hip_bfloat16 b = __float2bfloat16(f);
  unsigned short u;
  __builtin_memcpy(&u, &b, 2);
  return u;
}

// ---------------- x -> bf16 ----------------
__global__ void cvt_x_kernel(const float* __restrict__ x, bf16* __restrict__ xb, int n4) {
  int i = blockIdx.x * blockDim.x + threadIdx.x;
  if (i >= n4) return;
  float4 v = reinterpret_cast<const float4*>(x)[i];
  ushort4 o;
  o.x = f2bf_bits(v.x);
  o.y = f2bf_bits(v.y);
  o.z = f2bf_bits(v.z);
  o.w = f2bf_bits(v.w);
  reinterpret_cast<ushort4*>(xb)[i] = o;
}

// ---------------- transpose + convert: in [E][R][C] f32 -> out [E][C][R] bf16 ----------------
__global__ void transpose_cvt_kernel(const float* __restrict__ in, bf16* __restrict__ out,
                                     int R, int C) {
  __shared__ float tile[32][33];
  const size_t eoff = (size_t)blockIdx.z * R * C;
  const float* src = in + eoff;
  bf16* dst = out + eoff;
  int c0 = blockIdx.x * 32, r0 = blockIdx.y * 32;
  int tx = threadIdx.x, ty = threadIdx.y;  // (32, 8)
#pragma unroll
  for (int i = 0; i < 32; i += 8)
    tile[ty + i][tx] = src[(size_t)(r0 + ty + i) * C + (c0 + tx)];
  __syncthreads();
#pragma unroll
  for (int i = 0; i < 32; i += 8)
    dst[(size_t)(c0 + ty + i) * R + (r0 + tx)] = __float2bfloat16(tile[tx][ty + i]);
}

// ---------------- router: fp32 logits, top-2, softmax ----------------
__global__ void router_kernel(const float* __restrict__ x, const float* __restrict__ Wr,
                              int* __restrict__ idx, float* __restrict__ wtok,
                              int* __restrict__ cnt, int T) {
  int wave = (blockIdx.x * blockDim.x + threadIdx.x) >> 6;
  int lane = threadIdx.x & 63;
  if (wave >= T) return;
  const float* xr = x + (size_t)wave * TDIM;
  float acc[NEXP];
#pragma unroll
  for (int e = 0; e < NEXP; ++e) acc[e] = 0.f;
#pragma unroll
  for (int i = 0; i < TDIM / 64; ++i) {
    float xv = xr[lane + i * 64];
    const float* wr = Wr + (size_t)(lane + i * 64) * NEXP;
#pragma unroll
    for (int e = 0; e < NEXP; ++e) acc[e] += xv * wr[e];
  }
#pragma unroll
  for (int e = 0; e < NEXP; ++e) {
    float v = acc[e];
#pragma unroll
    for (int s = 32; s; s >>= 1) v += __shfl_xor(v, s);
    acc[e] = v;
  }
  if (lane == 0) {
    int e0 = 0;
    float l0 = acc[0];
    for (int e = 1; e < NEXP; ++e)
      if (acc[e] > l0) { l0 = acc[e]; e0 = e; }
    int e1 = -1;
    float l1 = -INFINITY;
    for (int e = 0; e < NEXP; ++e)
      if (e != e0 && acc[e] > l1) { l1 = acc[e]; e1 = e; }
    float z = __expf(l1 - l0);
    float w0 = 1.f / (1.f + z);
    float w1 = z / (1.f + z);
    idx[wave * 2] = e0;
    idx[wave * 2 + 1] = e1;
    wtok[wave * 2] = w0;
    wtok[wave * 2 + 1] = w1;
    atomicAdd(&cnt[e0], 1);
    atomicAdd(&cnt[e1], 1);
  }
}

__global__ void scan_kernel(const int* __restrict__ cnt, int* __restrict__ offs) {
  if (threadIdx.x == 0 && blockIdx.x == 0) {
    int s = 0;
    for (int e = 0; e < NEXP; ++e) { offs[e] = s; s += cnt[e]; }
  }
}

__global__ void build_perm_kernel(const int* __restrict__ idx, const float* __restrict__ wtok,
                                  const int* __restrict__ offs, int* __restrict__ fill,
                                  int* __restrict__ perm, float* __restrict__ wgrp, int T) {
  int t = blockIdx.x * blockDim.x + threadIdx.x;
  if (t >= T) return;
#pragma unroll
  for (int k = 0; k < 2; ++k) {
    int e = idx[t * 2 + k];
    int p = offs[e] + atomicAdd(&fill[e], 1);
    perm[p] = t;
    wgrp[p] = wtok[t * 2 + k];
  }
}

// ---------------- grouped GEMM, m97 structure ----------------
// C[m0+..][n0+..] for expert e = blockIdx.z. A rows gathered via perm (GEMM1) or
// contiguous grouped h rows (GEMM2). BT is [E][N][K] (pre-transposed).
template <int KD, int ND, bool GATHER, bool SCATTER>
__global__ __launch_bounds__(256) void moe_gemm(
    const bf16* __restrict__ A, const bf16* __restrict__ BT, const float* __restrict__ bias,
    const int* __restrict__ perm, const float* __restrict__ wgrp, const int* __restrict__ cnt,
    const int* __restrict__ offs, bf16* __restrict__ Hout, float* __restrict__ Out) {
  __shared__ short sA[128 * 32];
  __shared__ short sB[128 * 32];
  const int e = blockIdx.z;
  const int ce = cnt[e];
  const int m0 = blockIdx.y * 128;
  if (m0 >= ce) return;
  const int base = offs[e];
  const int n0 = blockIdx.x * 128;
  const int tid = threadIdx.x;
  const int wid = tid >> 6;
  const int lane = tid & 63;

  // staging pointers: thread handles linear slots tid and 256+tid (16B each)
  const int srow = tid >> 2;        // 0..63
  const int sch = (tid & 3) * 8;    // element offset in K
  const bf16 *aP0, *aP1;
  {
    int g0 = m0 + srow;
    if (g0 > ce - 1) g0 = ce - 1;
    int g1 = m0 + 64 + srow;
    if (g1 > ce - 1) g1 = ce - 1;
    if (GATHER) {
      aP0 = A + (size_t)perm[base + g0] * KD + sch;
      aP1 = A + (size_t)perm[base + g1] * KD + sch;
    } else {
      aP0 = A + (size_t)(base + g0) * KD + sch;
      aP1 = A + (size_t)(base + g1) * KD + sch;
    }
  }
  const bf16* bP0 = BT + ((size_t)e * ND + n0 + srow) * KD + sch;
  const bf16* bP1 = bP0 + (size_t)64 * KD;

  char* sAw = (char*)sA + wid * 1024;
  char* sBw = (char*)sB + wid * 1024;

  const int wm = wid >> 1, wn = wid & 1;
  const int lcol = lane & 15;
  const int lkg = (lane >> 4) * 8;
  const short* paBase = sA + (size_t)(wm * 64 + lcol) * 32 + lkg;
  const short* pbBase = sB + (size_t)(wn * 64 + lcol) * 32 + lkg;

  f32x4 acc[4][4];
#pragma unroll
  for (int m = 0; m < 4; ++m)
#pragma unroll
    for (int n = 0; n < 4; ++n) acc[m][n] = (f32x4){0.f, 0.f, 0.f, 0.f};

  for (int k0 = 0; k0 < KD; k0 += 32) {
    gload_lds16(sAw, aP0 + k0);
    gload_lds16(sAw + 4096, aP1 + k0);
    gload_lds16(sBw, bP0 + k0);
    gload_lds16(sBw + 4096, bP1 + k0);
    __syncthreads();
    bf16x8 af[4], bfr[4];
#pragma unroll
    for (int m = 0; m < 4; ++m) af[m] = *(const bf16x8*)(paBase + m * 16 * 32);
#pragma unroll
    for (int n = 0; n < 4; ++n) bfr[n] = *(const bf16x8*)(pbBase + n * 16 * 32);
#pragma unroll
    for (int m = 0; m < 4; ++m)
#pragma unroll
      for (int n = 0; n < 4; ++n)
        acc[m][n] = __builtin_amdgcn_mfma_f32_16x16x32_bf16(af[m], bfr[n], acc[m][n], 0, 0, 0);
    __syncthreads();
  }

  // epilogue. C mapping: row = wm*64 + m*16 + (lane>>4)*4 + r ; col = wn*64 + n*16 + (lane&15)
  const int lr4 = (lane >> 4) * 4;
  if (SCATTER) {
#pragma unroll
    for (int m = 0; m < 4; ++m)
#pragma unroll
      for (int r = 0; r < 4; ++r) {
        int grow = m0 + wm * 64 + m * 16 + lr4 + r;
        if (grow < ce) {
          int tok = perm[base + grow];
          float wv = wgrp[base + grow];
          float* orow = Out + (size_t)tok * ND;
#pragma unroll
          for (int n = 0; n < 4; ++n) {
            int col = n0 + wn * 64 + n * 16 + lcol;
            float v = acc[m][n][r] + bias[e * ND + col];
            atomicAdd(orow + col, wv * v);
          }
        }
      }
  } else {
#pragma unroll
    for (int m = 0; m < 4; ++m)
#pragma unroll
      for (int r = 0; r < 4; ++r) {
        int grow = m0 + wm * 64 + m * 16 + lr4 + r;
        if (grow < ce) {
          bf16* hrow = Hout + (size_t)(base + grow) * ND;
#pragma unroll
          for (int n = 0; n < 4; ++n) {
            int col = n0 + wn * 64 + n * 16 + lcol;
            float v = acc[m][n][r] + bias[e * ND + col];
            float g = 0.5f * v * (1.0f + erff(v * 0.70710678118654752f));
            hrow[col] = __float2bfloat16(g);
          }
        }
      }
  }
}

extern "C" void kernel_launch(void* const* d_in, const int* in_sizes, int n_in, void* d_out,
                              int out_size, void* d_ws, size_t ws_size, hipStream_t stream) {
  const float* x = (const float*)d_in[0];
  const float* Wr = (const float*)d_in[1];
  const float* W1 = (const float*)d_in[2];
  const float* b1 = (const float*)d_in[3];
  const float* W2 = (const float*)d_in[4];
  const float* b2 = (const float*)d_in[5];
  float* out = (float*)d_out;
  const int T = in_sizes[0] / TDIM;  // 8192

  size_t off = 0;
  auto alloc = [&](size_t bytes) {
    void* q = (char*)d_ws + off;
    off += (bytes + 255) & ~(size_t)255;
    return q;
  };
  bf16* xb = (bf16*)alloc((size_t)T * TDIM * 2);
  bf16* W1T = (bf16*)alloc((size_t)NEXP * TDIM * NHID * 2);
  bf16* W2T = (bf16*)alloc((size_t)NEXP * TDIM * NHID * 2);
  bf16* h = (bf16*)alloc((size_t)2 * T * NHID * 2);
  int* idx = (int*)alloc((size_t)T * 2 * 4);
  float* wtok = (float*)alloc((size_t)T * 2 * 4);
  int* perm = (int*)alloc((size_t)T * 2 * 4);
  float* wgrp = (float*)alloc((size_t)T * 2 * 4);
  int* cnt = (int*)alloc(256);   // cnt[8] | fill[8] | offs[8]
  int* fill = cnt + 8;
  int* offs = cnt + 16;

  hipMemsetAsync(d_out, 0, (size_t)out_size * 4, stream);
  hipMemsetAsync(cnt, 0, 64, stream);  // cnt + fill

  cvt_x_kernel<<<(T * TDIM / 4 + 255) / 256, 256, 0, stream>>>(x, xb, T * TDIM / 4);
  transpose_cvt_kernel<<<dim3(NHID / 32, TDIM / 32, NEXP), dim3(32, 8), 0, stream>>>(W1, W1T, TDIM,
                                                                                     NHID);
  transpose_cvt_kernel<<<dim3(TDIM / 32, NHID / 32, NEXP), dim3(32, 8), 0, stream>>>(W2, W2T, NHID,
                                                                                     TDIM);
  router_kernel<<<T / 4, 256, 0, stream>>>(x, Wr, idx, wtok, cnt, T);
  scan_kernel<<<1, 64, 0, stream>>>(cnt, offs);
  build_perm_kernel<<<(T + 255) / 256, 256, 0, stream>>>(idx, wtok, offs, fill, perm, wgrp, T);

  moe_gemm<TDIM, NHID, true, false>
      <<<dim3(NHID / 128, (T + 127) / 128, NEXP), 256, 0, stream>>>(xb, W1T, b1, perm, wgrp, cnt,
                                                                    offs, h, nullptr);
  moe_gemm<NHID, TDIM, false, true>
      <<<dim3(TDIM / 128, (T + 127) / 128, NEXP), 256, 0, stream>>>(h, W2T, b2, perm, wgrp, cnt,
                                                                    offs, nullptr, out);
}